// Round 5
// baseline (209.978 us; speedup 1.0000x reference)
//
#include <hip/hip_runtime.h>
#include <stdint.h>
#include <math.h>

#define IMG_H 2048
#define IMG_W 2048
#define CH_PIX (IMG_H * IMG_W)     // 4194304
#define MAXDET 4096
#define NBLK 1280                  // 5 channels * 256 row-tiles of 8 rows
#define FRONTIER 8192
#define CUT_LO (-0.8474f)          // logit(0.3) = -0.84729786 ; minus ~1e-4
#define CUT_HI (-0.8472f)          // plus ~1e-4
#define DELTA  (1e-4f)             // >> max sigmoid-rounding tie window (~1.8e-5)

__device__ __forceinline__ float sigmoidf_(float v) {
    return 1.0f / (1.0f + expf(-v));
}
__device__ __forceinline__ float sigthr_(float v) {
    float a = 1.0f / (1.0f + expf(-v));
    return a > 0.3f ? a : 0.0f;
}
__device__ __forceinline__ float max3_(float a, float b, float c) {
    return fmaxf(fmaxf(a, b), c);
}
__device__ __forceinline__ float maskv_(float v) {
    return v > CUT_HI ? v : -INFINITY;
}

// Pass A: logit-space conservative peak-candidate predicate. No transcendentals.
// Block = one channel x 8 rows; thread owns 8 contiguous cols; shfl col exchange;
// 1-row software prefetch.
__global__ __launch_bounds__(256) void pass_a(const float* __restrict__ feat,
                                              uint8_t* __restrict__ mask_bytes,
                                              unsigned* __restrict__ counts) {
    int blk = blockIdx.x;
    int c = blk >> 8, ytile = blk & 255;
    int y0 = ytile << 3;
    const float* chan = feat + (size_t)c * CH_PIX;
    int t = threadIdx.x, lane = t & 63;
    int xb = t << 3;
    int xe = (lane == 0) ? xb - 1 : xb + 8;
    bool edge_ok = ((lane == 0) || (lane == 63)) && ((unsigned)xe < (unsigned)IMG_W);

    auto load_raw = [&](int y, float* r, float& er) {
        if ((unsigned)y >= (unsigned)IMG_H) {
#pragma unroll
            for (int j = 0; j < 8; ++j) r[j] = -INFINITY;
            er = -INFINITY;
            return;
        }
        const float* row = chan + (size_t)y * IMG_W;
        float4 a = *(const float4*)(row + xb);
        float4 b = *(const float4*)(row + xb + 4);
        r[0] = a.x; r[1] = a.y; r[2] = a.z; r[3] = a.w;
        r[4] = b.x; r[5] = b.y; r[6] = b.z; r[7] = b.w;
        er = edge_ok ? row[xe] : -INFINITY;
    };

    float pa[8], pb[8], pc[8];   // masked (pool) values: rows r-1, r, r+1
    float rb[8], rc[8], rn[8];   // raw logits: row r (own), row r+1, prefetch
    float ea, eb, ec, etmp;

    load_raw(y0 - 1, rn, etmp);
#pragma unroll
    for (int j = 0; j < 8; ++j) pa[j] = maskv_(rn[j]);
    ea = maskv_(etmp);
    load_raw(y0, rb, etmp);
#pragma unroll
    for (int j = 0; j < 8; ++j) pb[j] = maskv_(rb[j]);
    eb = maskv_(etmp);
    load_raw(y0 + 1, rc, etmp);
#pragma unroll
    for (int j = 0; j < 8; ++j) pc[j] = maskv_(rc[j]);
    ec = maskv_(etmp);

    unsigned cnt = 0;
    size_t bb = (size_t)blk * 2048 + t;

#pragma unroll
    for (int r = 0; r < 8; ++r) {
        float en_ = -INFINITY;
        if (r < 7) load_raw(y0 + r + 2, rn, en_);   // prefetch next-next row
        float cm[8];
#pragma unroll
        for (int j = 0; j < 8; ++j) cm[j] = max3_(pa[j], pb[j], pc[j]);
        float cme = max3_(ea, eb, ec);
        float cmL = __shfl_up(cm[7], 1, 64);
        float cmR = __shfl_down(cm[0], 1, 64);
        if (lane == 0)  cmL = cme;
        if (lane == 63) cmR = cme;
        unsigned byte = 0;
#pragma unroll
        for (int j = 0; j < 8; ++j) {
            float l  = j       ? cm[j - 1] : cmL;
            float rr = (j < 7) ? cm[j + 1] : cmR;
            float wm = max3_(l, cm[j], rr);
            if (rb[j] > CUT_LO && wm <= rb[j] + DELTA) byte |= 1u << j;
        }
        mask_bytes[bb + (size_t)r * 256] = (uint8_t)byte;
        cnt += __popc(byte);
#pragma unroll
        for (int j = 0; j < 8; ++j) {
            pa[j] = pb[j]; pb[j] = pc[j]; pc[j] = maskv_(rn[j]);
            rb[j] = rc[j]; rc[j] = rn[j];
        }
        ea = eb; eb = ec; ec = maskv_(en_);
    }

#pragma unroll
    for (int off = 32; off; off >>= 1) cnt += __shfl_down(cnt, off, 64);
    __shared__ unsigned s4[4];
    if (lane == 0) s4[t >> 6] = cnt;
    __syncthreads();
    if (t == 0) counts[blk] = s4[0] + s4[1] + s4[2] + s4[3];
}

// Pass V: frontier blocks (candidate-prefix < FRONTIER) re-verify candidates
// exactly in libm-sigmoid space; in-place mask update + verified counts.
__global__ __launch_bounds__(256) void pass_v(const float* __restrict__ feat,
                                              uint64_t* __restrict__ masks,
                                              const unsigned* __restrict__ counts,
                                              unsigned* __restrict__ vcounts) {
    int blk = blockIdx.x, t = threadIdx.x, lane = t & 63, wave = t >> 6;
    unsigned p_lt = 0;
    for (int i = t; i < NBLK; i += 256) {
        unsigned v = counts[i];
        if (i < blk) p_lt += v;
    }
#pragma unroll
    for (int off = 32; off; off >>= 1) p_lt += __shfl_down(p_lt, off, 64);
    __shared__ unsigned sl[4];
    if (lane == 0) sl[wave] = p_lt;
    __syncthreads();
    unsigned boff = sl[0] + sl[1] + sl[2] + sl[3];
    if (boff >= FRONTIER) {
        if (t == 0) vcounts[blk] = counts[blk];
        return;
    }

    uint64_t w = masks[(size_t)blk * 256 + t];
    uint64_t vw = 0;
    uint32_t pbase = (uint32_t)blk * 16384u + (uint32_t)t * 64u;
    while (w) {
        int b = __ffsll((unsigned long long)w) - 1;
        w &= w - 1;
        uint32_t p = pbase + (uint32_t)b;
        int c = (int)(p >> 22);
        int rem = (int)(p & (CH_PIX - 1));
        int y = rem >> 11, x = rem & 2047;
        const float* chan = feat + (size_t)c * CH_PIX;
        float own = sigthr_(chan[(size_t)y * IMG_W + x]);
        if (own > 0.0f) {
            float pooled = own;
#pragma unroll
            for (int dy = -1; dy <= 1; ++dy) {
                int yy = y + dy;
                if ((unsigned)yy >= (unsigned)IMG_H) continue;
#pragma unroll
                for (int dx = -1; dx <= 1; ++dx) {
                    if (dy == 0 && dx == 0) continue;
                    int xx = x + dx;
                    if ((unsigned)xx >= (unsigned)IMG_W) continue;
                    pooled = fmaxf(pooled, sigthr_(chan[(size_t)yy * IMG_W + xx]));
                }
            }
            if (pooled == own) vw |= 1ull << b;
        }
    }
    masks[(size_t)blk * 256 + t] = vw;
    unsigned cnt = (unsigned)__popcll(vw);
#pragma unroll
    for (int off = 32; off; off >>= 1) cnt += __shfl_down(cnt, off, 64);
    __shared__ unsigned s4[4];
    if (lane == 0) s4[wave] = cnt;
    __syncthreads();
    if (t == 0) vcounts[blk] = s4[0] + s4[1] + s4[2] + s4[3];
}

// Pass B: offsets from verified counts; bit-loop emits pixel ids to LDS;
// parallel per-detection gather (exact libm sigmoids). Tail zero.
__global__ __launch_bounds__(256) void pass_b(const float* __restrict__ feat,
                                              const uint64_t* __restrict__ masks,
                                              const unsigned* __restrict__ vcounts,
                                              float* __restrict__ out) {
    int blk = blockIdx.x;
    int t = threadIdx.x;
    int wave = t >> 6, lane = t & 63;

    unsigned p_lt = 0, p_all = 0;
    for (int i = t; i < NBLK; i += 256) {
        unsigned v = vcounts[i];
        p_all += v;
        if (i < blk) p_lt += v;
    }
#pragma unroll
    for (int off = 32; off; off >>= 1) {
        p_lt  += __shfl_down(p_lt,  off, 64);
        p_all += __shfl_down(p_all, off, 64);
    }
    __shared__ unsigned sl[4], sa[4];
    if (lane == 0) { sl[wave] = p_lt; sa[wave] = p_all; }
    __syncthreads();
    unsigned boff  = sl[0] + sl[1] + sl[2] + sl[3];
    unsigned total = sa[0] + sa[1] + sa[2] + sa[3];

    if (blk == NBLK - 1) {           // zero the invalid tail
        unsigned start = total < MAXDET ? total : MAXDET;
        for (unsigned k = start + t; k < MAXDET; k += 256) {
            out[k] = 0.0f;
            out[MAXDET + 3 * k + 0] = 0.0f;
            out[MAXDET + 3 * k + 1] = 0.0f;
            out[MAXDET + 3 * k + 2] = 0.0f;
            out[4 * MAXDET + k] = 0.0f;
            out[5 * MAXDET + k] = 0.0f;
            out[6 * MAXDET + k] = 0.0f;
        }
    }
    if (boff >= MAXDET) return;      // uniform early exit for nearly all blocks

    uint64_t w = masks[(size_t)blk * 256 + t];
    unsigned cnt = (unsigned)__popcll(w);
    __shared__ unsigned tmp[256];
    __shared__ uint32_t det_lds[MAXDET];
    tmp[t] = cnt;
    __syncthreads();
    for (int off = 1; off < 256; off <<= 1) {
        unsigned u = (t >= off) ? tmp[t - off] : 0u;
        __syncthreads();
        tmp[t] += u;
        __syncthreads();
    }
    unsigned rank = boff + tmp[t] - cnt;
    unsigned bsum = tmp[255];
    uint32_t pbase = (uint32_t)blk * 16384u + (uint32_t)t * 64u;
    while (w) {                       // stores only -- fast even serial
        int b = __ffsll((unsigned long long)w) - 1;
        w &= w - 1;
        if (rank < MAXDET) det_lds[rank - boff] = pbase + (uint32_t)b;
        rank++;
    }
    __syncthreads();

    unsigned nend = boff + bsum; if (nend > MAXDET) nend = MAXDET;
    unsigned nloc = nend - boff;
    for (unsigned k = t; k < nloc; k += 256) {    // parallel independent gathers
        uint32_t p = det_lds[k];
        unsigned rk = boff + k;
        int c = (int)(p >> 22);
        int rem = (int)(p & (CH_PIX - 1));
        int y = rem >> 11, x = rem & 2047;
        size_t pix = (size_t)y * IMG_W + x;
        float pm = sigmoidf_(feat[pix]);
#pragma unroll
        for (int ch = 1; ch < 5; ++ch)
            pm = fmaxf(pm, sigmoidf_(feat[(size_t)ch * CH_PIX + pix]));
        float sdv = sigmoidf_(feat[(size_t)5 * CH_PIX + pix]);
        float szv = sigmoidf_(feat[(size_t)6 * CH_PIX + pix]);
        out[rk] = pm;
        out[MAXDET + 3 * rk + 0] = (float)c;
        out[MAXDET + 3 * rk + 1] = (float)y;
        out[MAXDET + 3 * rk + 2] = (float)x;
        out[4 * MAXDET + rk] = szv;   // size_width
        out[5 * MAXDET + rk] = szv;   // size_height
        out[6 * MAXDET + rk] = sdv;   // side_sel
    }
}

extern "C" void kernel_launch(void* const* d_in, const int* in_sizes, int n_in,
                              void* d_out, int out_size, void* d_ws, size_t ws_size,
                              hipStream_t stream) {
    const float* feat = (const float*)d_in[0];
    float* out = (float*)d_out;
    uint8_t* mask_bytes = (uint8_t*)d_ws;                         // 2.62 MB
    unsigned* counts  = (unsigned*)((char*)d_ws + (size_t)NBLK * 2048);
    unsigned* vcounts = counts + NBLK;

    pass_a<<<NBLK, 256, 0, stream>>>(feat, mask_bytes, counts);
    pass_v<<<NBLK, 256, 0, stream>>>(feat, (uint64_t*)d_ws, counts, vcounts);
    pass_b<<<NBLK, 256, 0, stream>>>(feat, (const uint64_t*)d_ws, vcounts, out);
}

// Round 6
// 209.743 us; speedup vs baseline: 1.0011x; 1.0011x over previous
//
#include <hip/hip_runtime.h>
#include <stdint.h>
#include <math.h>

#define IMG_H 2048
#define IMG_W 2048
#define CH_PIX (IMG_H * IMG_W)     // 4194304
#define MAXDET 4096
#define NBLK 1280                  // 5 channels * 256 row-tiles of 8 rows
#define FRONTIER 8192
#define CAP 4096                   // per-block candidate LDS capacity (expect ~1800)
#define MAGIC 0x5A5A0000u
#define CUT_LO (-0.8474f)          // logit(0.3) = -0.84729786 ; minus ~1e-4
#define CUT_HI (-0.8472f)          // plus ~1e-4
#define DELTA  (1e-4f)             // >> sigmoid f32 rounding-tie window (~3e-5 at |v|<=5.9)

__device__ __forceinline__ float sigmoidf_(float v) {
    return 1.0f / (1.0f + expf(-v));
}
__device__ __forceinline__ float sigthr_(float v) {
    float a = 1.0f / (1.0f + expf(-v));
    return a > 0.3f ? a : 0.0f;
}
__device__ __forceinline__ float max3_(float a, float b, float c) {
    return fmaxf(fmaxf(a, b), c);
}
__device__ __forceinline__ float maskv_(float v) {
    return v > CUT_HI ? v : -INFINITY;
}

// Pass A (unchanged from R5, proven absmax 0.0): logit-space conservative
// peak-candidate predicate. No transcendentals. Block = channel x 8 rows.
__global__ __launch_bounds__(256) void pass_a(const float* __restrict__ feat,
                                              uint8_t* __restrict__ mask_bytes,
                                              unsigned* __restrict__ counts) {
    int blk = blockIdx.x;
    int c = blk >> 8, ytile = blk & 255;
    int y0 = ytile << 3;
    const float* chan = feat + (size_t)c * CH_PIX;
    int t = threadIdx.x, lane = t & 63;
    int xb = t << 3;
    int xe = (lane == 0) ? xb - 1 : xb + 8;
    bool edge_ok = ((lane == 0) || (lane == 63)) && ((unsigned)xe < (unsigned)IMG_W);

    auto load_raw = [&](int y, float* r, float& er) {
        if ((unsigned)y >= (unsigned)IMG_H) {
#pragma unroll
            for (int j = 0; j < 8; ++j) r[j] = -INFINITY;
            er = -INFINITY;
            return;
        }
        const float* row = chan + (size_t)y * IMG_W;
        float4 a = *(const float4*)(row + xb);
        float4 b = *(const float4*)(row + xb + 4);
        r[0] = a.x; r[1] = a.y; r[2] = a.z; r[3] = a.w;
        r[4] = b.x; r[5] = b.y; r[6] = b.z; r[7] = b.w;
        er = edge_ok ? row[xe] : -INFINITY;
    };

    float pa[8], pb[8], pc[8];
    float rb[8], rc[8], rn[8];
    float ea, eb, ec, etmp;

    load_raw(y0 - 1, rn, etmp);
#pragma unroll
    for (int j = 0; j < 8; ++j) pa[j] = maskv_(rn[j]);
    ea = maskv_(etmp);
    load_raw(y0, rb, etmp);
#pragma unroll
    for (int j = 0; j < 8; ++j) pb[j] = maskv_(rb[j]);
    eb = maskv_(etmp);
    load_raw(y0 + 1, rc, etmp);
#pragma unroll
    for (int j = 0; j < 8; ++j) pc[j] = maskv_(rc[j]);
    ec = maskv_(etmp);

    unsigned cnt = 0;
    size_t bb = (size_t)blk * 2048 + t;

#pragma unroll
    for (int r = 0; r < 8; ++r) {
        float en_ = -INFINITY;
        if (r < 7) load_raw(y0 + r + 2, rn, en_);
        float cm[8];
#pragma unroll
        for (int j = 0; j < 8; ++j) cm[j] = max3_(pa[j], pb[j], pc[j]);
        float cme = max3_(ea, eb, ec);
        float cmL = __shfl_up(cm[7], 1, 64);
        float cmR = __shfl_down(cm[0], 1, 64);
        if (lane == 0)  cmL = cme;
        if (lane == 63) cmR = cme;
        unsigned byte = 0;
#pragma unroll
        for (int j = 0; j < 8; ++j) {
            float l  = j       ? cm[j - 1] : cmL;
            float rr = (j < 7) ? cm[j + 1] : cmR;
            float wm = max3_(l, cm[j], rr);
            if (rb[j] > CUT_LO && wm <= rb[j] + DELTA) byte |= 1u << j;
        }
        mask_bytes[bb + (size_t)r * 256] = (uint8_t)byte;
        cnt += __popc(byte);
#pragma unroll
        for (int j = 0; j < 8; ++j) {
            pa[j] = pb[j]; pb[j] = pc[j]; pc[j] = maskv_(rn[j]);
            rb[j] = rc[j]; rc[j] = rn[j];
        }
        ea = eb; eb = ec; ec = maskv_(en_);
    }

#pragma unroll
    for (int off = 32; off; off >>= 1) cnt += __shfl_down(cnt, off, 64);
    __shared__ unsigned s4a[4];
    if (lane == 0) s4a[t >> 6] = cnt;
    __syncthreads();
    if (t == 0) counts[blk] = s4a[0] + s4a[1] + s4a[2] + s4a[3];
}

__device__ __forceinline__ bool verify_peak(const float* __restrict__ feat, uint32_t p) {
    int c = (int)(p >> 22);
    int rem = (int)(p & (CH_PIX - 1));
    int y = rem >> 11, x = rem & 2047;
    const float* chan = feat + (size_t)c * CH_PIX;
    float own = sigthr_(chan[(size_t)y * IMG_W + x]);
    if (own <= 0.0f) return false;
    float pooled = own;
#pragma unroll
    for (int dy = -1; dy <= 1; ++dy) {
        int yy = y + dy;
        if ((unsigned)yy >= (unsigned)IMG_H) continue;
#pragma unroll
        for (int dx = -1; dx <= 1; ++dx) {
            if (dy == 0 && dx == 0) continue;
            int xx = x + dx;
            if ((unsigned)xx >= (unsigned)IMG_W) continue;
            pooled = fmaxf(pooled, sigthr_(chan[(size_t)yy * IMG_W + xx]));
        }
    }
    return pooled == own;
}

// Pass B: fused verify + ordered emit.
// Non-survivors (candidate-prefix >= FRONTIER) exit after the prefix reduce.
// Survivors: dump candidates->LDS, verify in parallel (strided), blocked LDS
// scan for exact ordered ranks, publish vcnt + spin on predecessor survivors
// (device-scope atomics; grid 1280 < resident capacity -> deadlock-free),
// then parallel gathers. Last survivor zeroes the tail.
__global__ __launch_bounds__(256) void pass_b(const float* __restrict__ feat,
                                              const uint64_t* __restrict__ masks,
                                              const unsigned* __restrict__ counts,
                                              unsigned* __restrict__ slots,
                                              float* __restrict__ out) {
    int blk = blockIdx.x, t = threadIdx.x, lane = t & 63, wave = t >> 6;

    __shared__ unsigned cnt_lds[256];
    __shared__ unsigned s4[4];
    unsigned p_lt = 0;
    for (int i = t; i < NBLK; i += 256) {
        unsigned v = counts[i];
        if (i == t) cnt_lds[t] = v;        // cache counts[0..255] for the pred walk
        if (i < blk) p_lt += v;
    }
#pragma unroll
    for (int off = 32; off; off >>= 1) p_lt += __shfl_down(p_lt, off, 64);
    if (lane == 0) s4[wave] = p_lt;
    __syncthreads();
    unsigned boff_c = s4[0] + s4[1] + s4[2] + s4[3];
    if (boff_c >= FRONTIER) return;        // uniform early exit: ~1272 of 1280 blocks

    unsigned cnt_own = (blk < 256) ? cnt_lds[blk] : counts[blk];
    bool is_last = (boff_c + cnt_own >= FRONTIER) || (blk == NBLK - 1);

    __shared__ unsigned short preds[64];
    __shared__ unsigned npreds_s, boffv_s;
    if (t == 0) {                          // survivor blk is small (~<=8): cheap walk
        unsigned np = 0, pfx = 0;
        for (int i = 0; i < blk && np < 64; ++i) {
            unsigned ci = (i < 256) ? cnt_lds[i] : counts[i];
            if (pfx < FRONTIER) preds[np++] = (unsigned short)i;
            pfx += ci;
        }
        npreds_s = np;
    }

    // 1) dump candidate pixel-ids to LDS in exact flat order (store-only bit loop)
    __shared__ unsigned tmp[256];
    __shared__ uint32_t det[CAP];
    __shared__ uint8_t valid[CAP];
    uint64_t w = masks[(size_t)blk * 256 + t];
    unsigned wc = (unsigned)__popcll(w);
    tmp[t] = wc;
    __syncthreads();
    for (int off = 1; off < 256; off <<= 1) {
        unsigned u = (t >= off) ? tmp[t - off] : 0u;
        __syncthreads();
        tmp[t] += u;
        __syncthreads();
    }
    unsigned wbase = tmp[t] - wc;
    unsigned ncand = tmp[255] < CAP ? tmp[255] : CAP;
    uint32_t pbase = (uint32_t)blk * 16384u + (uint32_t)t * 64u;
    {
        unsigned r = wbase;
        while (w) {
            int b = __ffsll((unsigned long long)w) - 1;
            w &= w - 1;
            if (r < CAP) det[r] = pbase + (uint32_t)b;
            r++;
        }
    }
    __syncthreads();

    // 2) parallel exact verification (strided: balanced, independent windows)
    for (unsigned k = t; k < ncand; k += 256)
        valid[k] = verify_peak(feat, det[k]) ? 1u : 0u;
    __syncthreads();

    // 3) blocked ordered scan of valid[] (16 per thread, all in LDS)
    unsigned myb = (unsigned)t * 16;
    unsigned ls = 0;
#pragma unroll
    for (int j = 0; j < 16; ++j) {
        unsigned k = myb + j;
        if (k < ncand) ls += valid[k];
    }
    tmp[t] = ls;
    __syncthreads();
    for (int off = 1; off < 256; off <<= 1) {
        unsigned u = (t >= off) ? tmp[t - off] : 0u;
        __syncthreads();
        tmp[t] += u;
        __syncthreads();
    }
    unsigned tbase = tmp[t] - ls;
    unsigned vtot = tmp[255];              // verified count, <= CAP, fits 16 bits

    // 4) publish own vcnt, then sum predecessor survivors' vcnts (thread 0)
    if (t == 0) {
        __threadfence();                   // device-scope release
        atomicExch(&slots[blk], MAGIC | vtot);
        unsigned sum = 0, np = npreds_s;
        for (unsigned u = 0; u < np; ++u) {
            unsigned idx = preds[u], v;
            while ((((v = atomicAdd(&slots[idx], 0u))) & 0xFFFF0000u) != MAGIC) { }
            sum += v & 0xFFFFu;
        }
        boffv_s = sum;
    }
    __syncthreads();
    unsigned boff_v = boffv_s;

    // 5) ordered emit with parallel gathers
    unsigned rk = boff_v + tbase;
#pragma unroll 4
    for (int j = 0; j < 16; ++j) {
        unsigned k = myb + j;
        if (k >= ncand) break;
        if (valid[k]) {
            if (rk < MAXDET) {
                uint32_t p = det[k];
                int c = (int)(p >> 22);
                int rem = (int)(p & (CH_PIX - 1));
                int y = rem >> 11, x = rem & 2047;
                size_t pix = (size_t)y * IMG_W + x;
                float pm = sigmoidf_(feat[pix]);
#pragma unroll
                for (int ch = 1; ch < 5; ++ch)
                    pm = fmaxf(pm, sigmoidf_(feat[(size_t)ch * CH_PIX + pix]));
                float sdv = sigmoidf_(feat[(size_t)5 * CH_PIX + pix]);
                float szv = sigmoidf_(feat[(size_t)6 * CH_PIX + pix]);
                out[rk] = pm;
                out[MAXDET + 3 * rk + 0] = (float)c;
                out[MAXDET + 3 * rk + 1] = (float)y;
                out[MAXDET + 3 * rk + 2] = (float)x;
                out[4 * MAXDET + rk] = szv;   // size_width
                out[5 * MAXDET + rk] = szv;   // size_height
                out[6 * MAXDET + rk] = sdv;   // side_sel
            }
            rk++;
        }
    }

    // 6) tail zero (no-op for this input: verified total >= MAXDET)
    if (is_last) {
        unsigned start = boff_v + vtot;
        if (start > MAXDET) start = MAXDET;
        for (unsigned k = start + t; k < MAXDET; k += 256) {
            out[k] = 0.0f;
            out[MAXDET + 3 * k + 0] = 0.0f;
            out[MAXDET + 3 * k + 1] = 0.0f;
            out[MAXDET + 3 * k + 2] = 0.0f;
            out[4 * MAXDET + k] = 0.0f;
            out[5 * MAXDET + k] = 0.0f;
            out[6 * MAXDET + k] = 0.0f;
        }
    }
}

extern "C" void kernel_launch(void* const* d_in, const int* in_sizes, int n_in,
                              void* d_out, int out_size, void* d_ws, size_t ws_size,
                              hipStream_t stream) {
    const float* feat = (const float*)d_in[0];
    float* out = (float*)d_out;
    uint8_t* mask_bytes = (uint8_t*)d_ws;                          // 2.62 MB
    unsigned* counts = (unsigned*)((char*)d_ws + (size_t)NBLK * 2048);
    unsigned* slots  = counts + NBLK;

    pass_a<<<NBLK, 256, 0, stream>>>(feat, mask_bytes, counts);
    pass_b<<<NBLK, 256, 0, stream>>>(feat, (const uint64_t*)d_ws, counts, slots, out);
}

// Round 7
// 181.812 us; speedup vs baseline: 1.1549x; 1.1536x over previous
//
#include <hip/hip_runtime.h>
#include <stdint.h>
#include <math.h>

#define IMG_H 2048
#define IMG_W 2048
#define CH_PIX (IMG_H * IMG_W)     // 4194304
#define MAXDET 4096
#define NBLK 1280                  // 5 channels * 256 row-tiles of 8 rows
#define CUT_LO (-0.8474f)          // < logit(0.3) = -0.84729786
#define CUT_HI (-0.8472f)          // > logit(0.3)
#define EPS    (1e-4f)             // > sigmoid f32 tie window for |v| <= 6
#define VSAFE  (6.0f)              // above this, sigmoid slope too flat: slow path

__device__ __forceinline__ float sigmoidf_(float v) {
    return 1.0f / (1.0f + expf(-v));
}
__device__ __forceinline__ float max3_(float a, float b, float c) {
    return fmaxf(fmaxf(a, b), c);
}

// K1: exact peak mask, logit-space fast path + rare inline sigmoid slow path.
// Block = one channel x 8 rows; thread owns 8 contiguous cols; shfl col
// exchange; 1-row software prefetch. Window max over RAW logits incl self.
__global__ __launch_bounds__(256) void pass_a(const float* __restrict__ feat,
                                              uint8_t* __restrict__ mask_bytes,
                                              unsigned* __restrict__ counts) {
    int blk = blockIdx.x;
    int c = blk >> 8, ytile = blk & 255;
    int y0 = ytile << 3;
    const float* chan = feat + (size_t)c * CH_PIX;
    int t = threadIdx.x, lane = t & 63;
    int xb = t << 3;
    int xe = (lane == 0) ? xb - 1 : xb + 8;
    bool edge_ok = ((lane == 0) || (lane == 63)) && ((unsigned)xe < (unsigned)IMG_W);

    auto load_raw = [&](int y, float* r, float& er) {
        if ((unsigned)y >= (unsigned)IMG_H) {
#pragma unroll
            for (int j = 0; j < 8; ++j) r[j] = -INFINITY;
            er = -INFINITY;
            return;
        }
        const float* row = chan + (size_t)y * IMG_W;
        float4 a = *(const float4*)(row + xb);
        float4 b = *(const float4*)(row + xb + 4);
        r[0] = a.x; r[1] = a.y; r[2] = a.z; r[3] = a.w;
        r[4] = b.x; r[5] = b.y; r[6] = b.z; r[7] = b.w;
        er = edge_ok ? row[xe] : -INFINITY;
    };

    float rp[8], rc_[8], rn[8];    // raw logit rows r-1, r, r+1
    float ep, ec, en;              // edge column raw values

    load_raw(y0 - 1, rp, ep);
    load_raw(y0,     rc_, ec);
    load_raw(y0 + 1, rn, en);

    unsigned cnt = 0;
    size_t bb = (size_t)blk * 2048 + t;

#pragma unroll
    for (int r = 0; r < 8; ++r) {
        float nx[8], enx = -INFINITY;
        if (r < 7) load_raw(y0 + r + 2, nx, enx);   // prefetch row r+2
        else {
#pragma unroll
            for (int j = 0; j < 8; ++j) nx[j] = -INFINITY;
        }
        float cm[8];
#pragma unroll
        for (int j = 0; j < 8; ++j) cm[j] = max3_(rp[j], rc_[j], rn[j]);
        float cme = max3_(ep, ec, en);
        float cmL = __shfl_up(cm[7], 1, 64);
        float cmR = __shfl_down(cm[0], 1, 64);
        if (lane == 0)  cmL = cme;
        if (lane == 63) cmR = cme;

        unsigned byte = 0;
#pragma unroll
        for (int j = 0; j < 8; ++j) {
            float own = rc_[j];
            float l  = j       ? cm[j - 1] : cmL;
            float rr = (j < 7) ? cm[j + 1] : cmR;
            float wm = max3_(l, cm[j], rr);        // >= own (includes self)
            bool cand;
            if (own > CUT_HI && wm <= own) {
                cand = true;                        // definite peak
            } else if (own <= CUT_LO) {
                cand = false;                       // definitely below threshold
            } else if (own > CUT_HI && wm > own + EPS && own <= VSAFE) {
                cand = false;                       // definite strictly-greater nb
            } else {
                // rare (~1e-4 of pixels): exact sigmoid-space decision
                float so = sigmoidf_(own);
                cand = (so > 0.3f) && (sigmoidf_(wm) <= so);
            }
            if (cand) byte |= 1u << j;
        }
        mask_bytes[bb + (size_t)r * 256] = (uint8_t)byte;
        cnt += __popc(byte);
#pragma unroll
        for (int j = 0; j < 8; ++j) { rp[j] = rc_[j]; rc_[j] = rn[j]; rn[j] = nx[j]; }
        ep = ec; ec = en; en = enx;
    }

#pragma unroll
    for (int off = 32; off; off >>= 1) cnt += __shfl_down(cnt, off, 64);
    __shared__ unsigned s4[4];
    if (lane == 0) s4[t >> 6] = cnt;
    __syncthreads();
    if (t == 0) counts[blk] = s4[0] + s4[1] + s4[2] + s4[3];
}

// K2 (verbatim R3 pass_b, measured-good): offsets from counts; bit-loop emits
// pixel ids to LDS (store-only); parallel per-detection gather. Tail zero.
__global__ __launch_bounds__(256) void pass_b(const float* __restrict__ feat,
                                              const uint64_t* __restrict__ masks,
                                              const unsigned* __restrict__ counts,
                                              float* __restrict__ out) {
    int blk = blockIdx.x;
    int t = threadIdx.x;
    int wave = t >> 6, lane = t & 63;

    unsigned p_lt = 0, p_all = 0;
    for (int i = t; i < NBLK; i += 256) {
        unsigned v = counts[i];
        p_all += v;
        if (i < blk) p_lt += v;
    }
#pragma unroll
    for (int off = 32; off; off >>= 1) {
        p_lt  += __shfl_down(p_lt,  off, 64);
        p_all += __shfl_down(p_all, off, 64);
    }
    __shared__ unsigned sl[4], sa[4];
    if (lane == 0) { sl[wave] = p_lt; sa[wave] = p_all; }
    __syncthreads();
    unsigned boff  = sl[0] + sl[1] + sl[2] + sl[3];
    unsigned total = sa[0] + sa[1] + sa[2] + sa[3];

    if (blk == NBLK - 1) {           // zero the invalid tail
        unsigned start = total < MAXDET ? total : MAXDET;
        for (unsigned k = start + t; k < MAXDET; k += 256) {
            out[k] = 0.0f;
            out[MAXDET + 3 * k + 0] = 0.0f;
            out[MAXDET + 3 * k + 1] = 0.0f;
            out[MAXDET + 3 * k + 2] = 0.0f;
            out[4 * MAXDET + k] = 0.0f;
            out[5 * MAXDET + k] = 0.0f;
            out[6 * MAXDET + k] = 0.0f;
        }
    }
    if (boff >= MAXDET) return;      // uniform early exit for nearly all blocks

    uint64_t w = masks[(size_t)blk * 256 + t];
    unsigned cnt = (unsigned)__popcll(w);
    __shared__ unsigned tmp[256];
    __shared__ uint32_t det_lds[MAXDET];
    tmp[t] = cnt;
    __syncthreads();
    for (int off = 1; off < 256; off <<= 1) {
        unsigned u = (t >= off) ? tmp[t - off] : 0u;
        __syncthreads();
        tmp[t] += u;
        __syncthreads();
    }
    unsigned rank = boff + tmp[t] - cnt;
    unsigned bsum = tmp[255];
    uint32_t pbase = (uint32_t)blk * 16384u + (uint32_t)t * 64u;
    while (w) {                       // stores only -- fast even serial
        int b = __ffsll((unsigned long long)w) - 1;
        w &= w - 1;
        if (rank < MAXDET) det_lds[rank - boff] = pbase + (uint32_t)b;
        rank++;
    }
    __syncthreads();

    unsigned nend = boff + bsum; if (nend > MAXDET) nend = MAXDET;
    unsigned nloc = nend - boff;
    for (unsigned k = t; k < nloc; k += 256) {    // parallel independent gathers
        uint32_t p = det_lds[k];
        unsigned rk = boff + k;
        int c = (int)(p >> 22);
        int rem = (int)(p & (CH_PIX - 1));
        int y = rem >> 11, x = rem & 2047;
        size_t pix = (size_t)y * IMG_W + x;
        float pm = sigmoidf_(feat[pix]);
#pragma unroll
        for (int ch = 1; ch < 5; ++ch)
            pm = fmaxf(pm, sigmoidf_(feat[(size_t)ch * CH_PIX + pix]));
        float sdv = sigmoidf_(feat[(size_t)5 * CH_PIX + pix]);
        float szv = sigmoidf_(feat[(size_t)6 * CH_PIX + pix]);
        out[rk] = pm;
        out[MAXDET + 3 * rk + 0] = (float)c;
        out[MAXDET + 3 * rk + 1] = (float)y;
        out[MAXDET + 3 * rk + 2] = (float)x;
        out[4 * MAXDET + rk] = szv;   // size_width
        out[5 * MAXDET + rk] = szv;   // size_height
        out[6 * MAXDET + rk] = sdv;   // side_sel
    }
}

extern "C" void kernel_launch(void* const* d_in, const int* in_sizes, int n_in,
                              void* d_out, int out_size, void* d_ws, size_t ws_size,
                              hipStream_t stream) {
    const float* feat = (const float*)d_in[0];
    float* out = (float*)d_out;
    uint8_t* mask_bytes = (uint8_t*)d_ws;                         // 2.62 MB
    unsigned* counts = (unsigned*)((char*)d_ws + (size_t)NBLK * 2048);

    pass_a<<<NBLK, 256, 0, stream>>>(feat, mask_bytes, counts);
    pass_b<<<NBLK, 256, 0, stream>>>(feat, (const uint64_t*)d_ws, counts, out);
}

// Round 8
// 180.163 us; speedup vs baseline: 1.1655x; 1.0092x over previous
//
#include <hip/hip_runtime.h>
#include <stdint.h>
#include <math.h>

#define IMG_H 2048
#define IMG_W 2048
#define CH_PIX (IMG_H * IMG_W)     // 4194304
#define MAXDET 4096
#define NBLK 1280                  // 5 channels * 256 row-tiles of 8 rows
#define CUT_LO (-0.8474f)          // < logit(0.3) = -0.84729786
#define CUT_HI (-0.8472f)          // > logit(0.3)
#define EPS    (1e-4f)             // > sigmoid f32 tie window for |v| <= 6
#define VSAFE  (6.0f)              // above this, sigmoid slope too flat: slow path

__device__ __forceinline__ float sigmoidf_(float v) {
    return 1.0f / (1.0f + expf(-v));
}
__device__ __forceinline__ float max3_(float a, float b, float c) {
    return fmaxf(fmaxf(a, b), c);
}

// K1: exact peak mask, logit-space fast path + rare inline sigmoid slow path.
// Block = one channel x 8 rows. FULL-TILE PREFETCH: all 10 rows (20x dwordx4)
// issued back-to-back before any compute -> 320 B/lane in flight, BW-bound.
__global__ __launch_bounds__(256) void pass_a(const float* __restrict__ feat,
                                              uint8_t* __restrict__ mask_bytes,
                                              unsigned* __restrict__ counts) {
    int blk = blockIdx.x;
    int c = blk >> 8, ytile = blk & 255;
    int y0 = ytile << 3;
    const float* chan = feat + (size_t)c * CH_PIX;
    int t = threadIdx.x, lane = t & 63;
    int xb = t << 3;
    int xe = (lane == 0) ? xb - 1 : xb + 8;
    bool edge_ok = ((lane == 0) || (lane == 63)) && ((unsigned)xe < (unsigned)IMG_W);

    float row[10][8];              // raw logits, reg row i = image row y0-1+i
    float edge[10];                // boundary-lane extra column

    // ---- prologue: issue ALL loads, no interleaved compute ----
#pragma unroll
    for (int i = 0; i < 10; ++i) {
        int y = y0 - 1 + i;
        if ((unsigned)y < (unsigned)IMG_H) {
            const float* rp = chan + (size_t)y * IMG_W;
            float4 a = *(const float4*)(rp + xb);
            float4 b = *(const float4*)(rp + xb + 4);
            row[i][0] = a.x; row[i][1] = a.y; row[i][2] = a.z; row[i][3] = a.w;
            row[i][4] = b.x; row[i][5] = b.y; row[i][6] = b.z; row[i][7] = b.w;
            edge[i] = edge_ok ? rp[xe] : -INFINITY;
        } else {
#pragma unroll
            for (int j = 0; j < 8; ++j) row[i][j] = -INFINITY;
            edge[i] = -INFINITY;
        }
    }

    unsigned cnt = 0;
    size_t bb = (size_t)blk * 2048 + t;

    // ---- compute all 8 output rows from registers ----
#pragma unroll
    for (int r = 0; r < 8; ++r) {
        float cm[8];
#pragma unroll
        for (int j = 0; j < 8; ++j)
            cm[j] = max3_(row[r][j], row[r + 1][j], row[r + 2][j]);
        float cme = max3_(edge[r], edge[r + 1], edge[r + 2]);
        float cmL = __shfl_up(cm[7], 1, 64);
        float cmR = __shfl_down(cm[0], 1, 64);
        if (lane == 0)  cmL = cme;
        if (lane == 63) cmR = cme;

        unsigned byte = 0;
#pragma unroll
        for (int j = 0; j < 8; ++j) {
            float own = row[r + 1][j];
            float l  = j       ? cm[j - 1] : cmL;
            float rr = (j < 7) ? cm[j + 1] : cmR;
            float wm = max3_(l, cm[j], rr);        // >= own (includes self)
            bool cand;
            if (own > CUT_HI && wm <= own) {
                cand = true;                        // definite peak
            } else if (own <= CUT_LO) {
                cand = false;                       // definitely below threshold
            } else if (own > CUT_HI && wm > own + EPS && own <= VSAFE) {
                cand = false;                       // definite strictly-greater nb
            } else {
                // rare (~1e-4 of pixels): exact sigmoid-space decision
                float so = sigmoidf_(own);
                cand = (so > 0.3f) && (sigmoidf_(wm) <= so);
            }
            if (cand) byte |= 1u << j;
        }
        mask_bytes[bb + (size_t)r * 256] = (uint8_t)byte;
        cnt += __popc(byte);
    }

#pragma unroll
    for (int off = 32; off; off >>= 1) cnt += __shfl_down(cnt, off, 64);
    __shared__ unsigned s4[4];
    if (lane == 0) s4[t >> 6] = cnt;
    __syncthreads();
    if (t == 0) counts[blk] = s4[0] + s4[1] + s4[2] + s4[3];
}

// K2 (verbatim R3/R7 pass_b, measured-good): offsets from counts; bit-loop
// emits pixel ids to LDS (store-only); parallel per-detection gather. Tail zero.
__global__ __launch_bounds__(256) void pass_b(const float* __restrict__ feat,
                                              const uint64_t* __restrict__ masks,
                                              const unsigned* __restrict__ counts,
                                              float* __restrict__ out) {
    int blk = blockIdx.x;
    int t = threadIdx.x;
    int wave = t >> 6, lane = t & 63;

    unsigned p_lt = 0, p_all = 0;
    for (int i = t; i < NBLK; i += 256) {
        unsigned v = counts[i];
        p_all += v;
        if (i < blk) p_lt += v;
    }
#pragma unroll
    for (int off = 32; off; off >>= 1) {
        p_lt  += __shfl_down(p_lt,  off, 64);
        p_all += __shfl_down(p_all, off, 64);
    }
    __shared__ unsigned sl[4], sa[4];
    if (lane == 0) { sl[wave] = p_lt; sa[wave] = p_all; }
    __syncthreads();
    unsigned boff  = sl[0] + sl[1] + sl[2] + sl[3];
    unsigned total = sa[0] + sa[1] + sa[2] + sa[3];

    if (blk == NBLK - 1) {           // zero the invalid tail
        unsigned start = total < MAXDET ? total : MAXDET;
        for (unsigned k = start + t; k < MAXDET; k += 256) {
            out[k] = 0.0f;
            out[MAXDET + 3 * k + 0] = 0.0f;
            out[MAXDET + 3 * k + 1] = 0.0f;
            out[MAXDET + 3 * k + 2] = 0.0f;
            out[4 * MAXDET + k] = 0.0f;
            out[5 * MAXDET + k] = 0.0f;
            out[6 * MAXDET + k] = 0.0f;
        }
    }
    if (boff >= MAXDET) return;      // uniform early exit for nearly all blocks

    uint64_t w = masks[(size_t)blk * 256 + t];
    unsigned cnt = (unsigned)__popcll(w);
    __shared__ unsigned tmp[256];
    __shared__ uint32_t det_lds[MAXDET];
    tmp[t] = cnt;
    __syncthreads();
    for (int off = 1; off < 256; off <<= 1) {
        unsigned u = (t >= off) ? tmp[t - off] : 0u;
        __syncthreads();
        tmp[t] += u;
        __syncthreads();
    }
    unsigned rank = boff + tmp[t] - cnt;
    unsigned bsum = tmp[255];
    uint32_t pbase = (uint32_t)blk * 16384u + (uint32_t)t * 64u;
    while (w) {                       // stores only -- fast even serial
        int b = __ffsll((unsigned long long)w) - 1;
        w &= w - 1;
        if (rank < MAXDET) det_lds[rank - boff] = pbase + (uint32_t)b;
        rank++;
    }
    __syncthreads();

    unsigned nend = boff + bsum; if (nend > MAXDET) nend = MAXDET;
    unsigned nloc = nend - boff;
    for (unsigned k = t; k < nloc; k += 256) {    // parallel independent gathers
        uint32_t p = det_lds[k];
        unsigned rk = boff + k;
        int c = (int)(p >> 22);
        int rem = (int)(p & (CH_PIX - 1));
        int y = rem >> 11, x = rem & 2047;
        size_t pix = (size_t)y * IMG_W + x;
        float pm = sigmoidf_(feat[pix]);
#pragma unroll
        for (int ch = 1; ch < 5; ++ch)
            pm = fmaxf(pm, sigmoidf_(feat[(size_t)ch * CH_PIX + pix]));
        float sdv = sigmoidf_(feat[(size_t)5 * CH_PIX + pix]);
        float szv = sigmoidf_(feat[(size_t)6 * CH_PIX + pix]);
        out[rk] = pm;
        out[MAXDET + 3 * rk + 0] = (float)c;
        out[MAXDET + 3 * rk + 1] = (float)y;
        out[MAXDET + 3 * rk + 2] = (float)x;
        out[4 * MAXDET + rk] = szv;   // size_width
        out[5 * MAXDET + rk] = szv;   // size_height
        out[6 * MAXDET + rk] = sdv;   // side_sel
    }
}

extern "C" void kernel_launch(void* const* d_in, const int* in_sizes, int n_in,
                              void* d_out, int out_size, void* d_ws, size_t ws_size,
                              hipStream_t stream) {
    const float* feat = (const float*)d_in[0];
    float* out = (float*)d_out;
    uint8_t* mask_bytes = (uint8_t*)d_ws;                         // 2.62 MB
    unsigned* counts = (unsigned*)((char*)d_ws + (size_t)NBLK * 2048);

    pass_a<<<NBLK, 256, 0, stream>>>(feat, mask_bytes, counts);
    pass_b<<<NBLK, 256, 0, stream>>>(feat, (const uint64_t*)d_ws, counts, out);
}